// Round 1
// baseline (154.004 us; speedup 1.0000x reference)
//
#include <hip/hip_runtime.h>
#include <hip/hip_bf16.h>

namespace {
constexpr int NG = 4096;   // grid points per batch (64*64)
constexpr int NTt = 4096;  // target points
constexpr int DZc = 128;
constexpr int NKc = 2;
constexpr int GT = 32;     // g per K-chunk
constexpr int NCHUNK = NG / GT;

typedef __attribute__((ext_vector_type(8))) short bf16x8;
typedef __attribute__((ext_vector_type(4))) short short4v;
typedef __attribute__((ext_vector_type(4))) float f32x4;

__device__ __forceinline__ short f2bf(float x) {
    __hip_bfloat16 h = __float2bfloat16(x);
    return __builtin_bit_cast(short, h);
}
}

// Block: 256 thr (4 waves), tile = 64t x 128d x 2k for one b.
// Waves: wt = t-half (32t), wd = d-half (64d). MFMA 16x16x32 bf16.
// LDS: z^T chunk [128 d][32 g] bf16, XOR-swizzled in 16B blocks; double-buffered.
__global__ __launch_bounds__(256, 1)
void setconv_fused(const float* __restrict__ xgrid, const float* __restrict__ zgrid,
                   const float* __restrict__ xt, const float* __restrict__ lsp,
                   float* __restrict__ out)
{
    __shared__ __align__(16) short zt[2][DZc * GT];   // 2 x 8 KB
    __shared__ __align__(16) float xgf[2][GT * 2];    // xg chunk (x,y interleaved)

    const int tid  = threadIdx.x;
    const int lane = tid & 63;
    const int wid  = tid >> 6;
    const int wt = wid >> 1;
    const int wd = wid & 1;
    const int hi = lane >> 4;   // 0..3 (lane group)
    const int lm = lane & 15;

    // XCD swizzle: 256 blocks -> each XCD serves exactly one b (z[b]=2MB fits 4MB L2)
    const int lb = ((blockIdx.x & 7) << 5) | (blockIdx.x >> 3);
    const int b  = lb >> 6;
    const int t0 = (lb & 63) << 6;

    // lengthscale -> exp2 coefficients a[dim][k] = -0.5*log2(e)/ls^2
    float a00, a01, a10, a11;
    {
        const float LOG2E = 1.4426950408889634f;
        float c[2][2];
#pragma unroll
        for (int d = 0; d < 2; ++d)
#pragma unroll
            for (int k = 0; k < 2; ++k) {
                float p  = lsp[d * 2 + k];
                float sp = fmaxf(p, 0.0f) + log1pf(__expf(-fabsf(p)));
                float ls = 1e-5f + sp;
                c[d][k]  = -0.5f * LOG2E / (ls * ls);
            }
        a00 = c[0][0]; a01 = c[0][1]; a10 = c[1][0]; a11 = c[1][1];
    }

    // xt coords for this lane's two 16-row t-subtiles
    float xtx[2], xty[2];
#pragma unroll
    for (int ts = 0; ts < 2; ++ts) {
        int t = t0 + wt * 32 + ts * 16 + lm;
        const float* p = &xt[((long)b * NTt + t) * 2];
        xtx[ts] = p[0]; xty[ts] = p[1];
    }

    f32x4 acc[2][4][2];
#pragma unroll
    for (int ts = 0; ts < 2; ++ts)
#pragma unroll
        for (int db = 0; db < 4; ++db)
#pragma unroll
            for (int k = 0; k < 2; ++k)
                acc[ts][db][k] = (f32x4){0.f, 0.f, 0.f, 0.f};

    // staging assignment: thread -> (d column, two 8-g slices)
    const int dcol = tid & 127;
    const int g8a  = tid >> 7;          // 0/1 -> slices g8a and g8a+2
    const long zbase = (long)b * NG * DZc;
    const int swz = (dcol >> 1) & 3;
    const int soff0 = dcol * 32 + ((g8a       ^ swz) * 8);  // shorts
    const int soff1 = dcol * 32 + (((g8a + 2) ^ swz) * 8);

    float zv[16];
    float xgv = 0.f;

    auto stage_load = [&](int c) {
        const int g0 = c * GT;
        const float* zc0 = zgrid + zbase + (long)(g0 + g8a * 8) * DZc + dcol;
        const float* zc1 = zgrid + zbase + (long)(g0 + (g8a + 2) * 8) * DZc + dcol;
#pragma unroll
        for (int j = 0; j < 8; ++j) zv[j] = zc0[j * DZc];
#pragma unroll
        for (int j = 0; j < 8; ++j) zv[8 + j] = zc1[j * DZc];
        if (wid == 0) xgv = xgrid[((long)b * NG + g0) * 2 + tid];
    };

    auto stage_store = [&](int buf) {
        bf16x8 p0, p1;
#pragma unroll
        for (int j = 0; j < 8; ++j) { p0[j] = f2bf(zv[j]); p1[j] = f2bf(zv[8 + j]); }
        *(bf16x8*)&zt[buf][soff0] = p0;
        *(bf16x8*)&zt[buf][soff1] = p1;
        if (wid == 0) xgf[buf][tid] = xgv;
    };

    auto compute = [&](int buf) {
        // B fragments (z^T): elem j <-> g-slot f(hi,j) = hi*4 + (j&3) + (j>>2)*16
        bf16x8 Bf[4];
#pragma unroll
        for (int db = 0; db < 4; ++db) {
            const int d = wd * 64 + db * 16 + lm;
            const short* zb = &zt[buf][d * 32];
            const int q = hi ^ (lm & 6);     // swizzled 4-g block (d&6 == lm&6)
            short4v lo = *(const short4v*)(zb + q * 4);
            short4v hh = *(const short4v*)(zb + (q ^ 4) * 4);
            Bf[db] = (bf16x8){lo.x, lo.y, lo.z, lo.w, hh.x, hh.y, hh.z, hh.w};
        }
        // xg pairs for the same 8 g-slots (broadcast reads)
        const float4* xp  = (const float4*)&xgf[buf][hi * 8];
        const float4* xp2 = (const float4*)&xgf[buf][32 + hi * 8];
        float4 x01 = xp[0],  x23 = xp[1];
        float4 x45 = xp2[0], x67 = xp2[1];
        float gx[8] = {x01.x, x01.z, x23.x, x23.z, x45.x, x45.z, x67.x, x67.z};
        float gy[8] = {x01.y, x01.w, x23.y, x23.w, x45.y, x45.w, x67.y, x67.w};
#pragma unroll
        for (int ts = 0; ts < 2; ++ts) {
            bf16x8 A0, A1;   // W fragments for k=0,1 (same f mapping as Bf)
#pragma unroll
            for (int j = 0; j < 8; ++j) {
                float dx = xtx[ts] - gx[j];
                float dy = xty[ts] - gy[j];
                float s0 = dx * dx, s1 = dy * dy;
                float e0 = s0 * a00 + s1 * a10;
                float e1 = s0 * a01 + s1 * a11;
                A0[j] = f2bf(exp2f(e0));
                A1[j] = f2bf(exp2f(e1));
            }
#pragma unroll
            for (int db = 0; db < 4; ++db) {
                acc[ts][db][0] = __builtin_amdgcn_mfma_f32_16x16x32_bf16(A0, Bf[db], acc[ts][db][0], 0, 0, 0);
                acc[ts][db][1] = __builtin_amdgcn_mfma_f32_16x16x32_bf16(A1, Bf[db], acc[ts][db][1], 0, 0, 0);
            }
        }
    };

    stage_load(0);
    stage_store(0);
    __syncthreads();

    for (int c = 0; c < NCHUNK; ++c) {
        const int cur = c & 1;
        const int nxt = cur ^ 1;
        if (c + 1 < NCHUNK) stage_load(c + 1);   // issue early: HBM/L2 latency hides under compute
        compute(cur);
        if (c + 1 < NCHUNK) stage_store(nxt);    // write late (T14 async-stage split)
        __syncthreads();
    }

    // epilogue: C/D layout col=lane&15 (=d), row=(lane>>4)*4+r (=t); pack k-pair as float2
#pragma unroll
    for (int ts = 0; ts < 2; ++ts)
#pragma unroll
        for (int db = 0; db < 4; ++db) {
            const int d = wd * 64 + db * 16 + lm;
#pragma unroll
            for (int r = 0; r < 4; ++r) {
                const int t = t0 + wt * 32 + ts * 16 + hi * 4 + r;
                float2 v = {acc[ts][db][0][r], acc[ts][db][1][r]};
                *(float2*)&out[((long)(b * NTt + t) * DZc + d) * NKc] = v;
            }
        }
}

extern "C" void kernel_launch(void* const* d_in, const int* in_sizes, int n_in,
                              void* d_out, int out_size, void* d_ws, size_t ws_size,
                              hipStream_t stream) {
    const float* xg  = (const float*)d_in[0];   // x_grid [4,64,64,2]
    const float* zg  = (const float*)d_in[1];   // z_grid [4,64,64,128]
    const float* xtp = (const float*)d_in[2];   // xt     [4,4096,2]
    const float* ls  = (const float*)d_in[3];   // lengthscale_param [2,2]
    float* o = (float*)d_out;                   // [4,4096,256] fp32
    dim3 grid(256), block(256);
    hipLaunchKernelGGL(setconv_fused, grid, block, 0, stream, xg, zg, xtp, ls, o);
}

// Round 2
// 137.856 us; speedup vs baseline: 1.1171x; 1.1171x over previous
//
#include <hip/hip_runtime.h>
#include <hip/hip_bf16.h>

namespace {
constexpr int NG  = 4096;   // grid points per batch
constexpr int NTt = 4096;   // target points
constexpr int DZc = 128;
constexpr int NKc = 2;
constexpr int GT  = 64;     // g per chunk (main kernel)
constexpr int NCH = NG / GT;
constexpr long IMG_CHUNK_B = (long)DZc * GT * 2;          // 16384 B per chunk image
constexpr long IMG_BYTES   = 4L * NCH * IMG_CHUNK_B;      // 4.19 MB

typedef __attribute__((ext_vector_type(8))) short bf16x8;
typedef __attribute__((ext_vector_type(4))) short short4v;
typedef __attribute__((ext_vector_type(4))) float f32x4;

__device__ __forceinline__ short f2bf(float x) {
    __hip_bfloat16 h = __float2bfloat16(x);
    return __builtin_bit_cast(short, h);
}

__device__ __forceinline__ void gload16(const void* g, void* lds) {
    __builtin_amdgcn_global_load_lds(
        (const __attribute__((address_space(1))) void*)g,
        (__attribute__((address_space(3))) void*)lds, 16, 0, 0);
}
}

// ---------------------------------------------------------------------------
// Pre-kernel: z fp32 [b][g][128] -> bf16 chunk images in ws.
// Image chunk (b,c): 128 d-rows x 64 g-slots bf16 (row = 128B), st_16x32
// pre-swizzled: physical byte y holds logical byte y ^ (((y>>9)&1)<<5),
// logical = d*128 + s*2, value = z[b][c*64+s][d].
// ---------------------------------------------------------------------------
__global__ __launch_bounds__(256)
void zcvt_kernel(const float* __restrict__ zg, short* __restrict__ img)
{
    __shared__ float tile[GT * DZc];   // [s][d] fp32, 32 KB
    const int tid = threadIdx.x;
    const int blk = blockIdx.x;        // 256 = 4 b x 64 c
    const int c = blk & 63, b = blk >> 6;
    const float* zb = zg + ((long)(b * NG + c * GT)) * DZc;
#pragma unroll
    for (int it = 0; it < 8; ++it) {
        int f = tid + it * 256;        // 2048 float4 tiles
        int s = f >> 5, dq = f & 31;
        float4 v = *(const float4*)(zb + (long)s * DZc + dq * 4);
        *(float4*)&tile[s * DZc + dq * 4] = v;
    }
    __syncthreads();
    char* ib = (char*)img + (long)blk * IMG_CHUNK_B;
#pragma unroll
    for (int it = 0; it < 4; ++it) {
        int p = tid + it * 256;        // 16B block id 0..1023
        int y = p * 16;
        int l = y ^ (((y >> 9) & 1) << 5);
        int d  = l >> 7;
        int s0 = (l & 127) >> 1;
        bf16x8 o;
#pragma unroll
        for (int j = 0; j < 8; ++j) o[j] = f2bf(tile[(s0 + j) * DZc + d]);
        *(bf16x8*)(ib + y) = o;
    }
}

// ---------------------------------------------------------------------------
// Main kernel: 256 blocks (b, 64t-tile) x 512 threads (8 waves: 4 wt x 2 wd).
// Wave = 16t x 64d, K-loop over 64 chunks of 64 g. Staging = global_load_lds
// from the pre-built image (linear), B-frag reads st_16x32-swizzled b128.
// ---------------------------------------------------------------------------
__global__ __launch_bounds__(512, 2)
void setconv_main(const float* __restrict__ xgrid, const float* __restrict__ xt,
                  const float* __restrict__ lsp, const short* __restrict__ zimg,
                  float* __restrict__ out)
{
    __shared__ __align__(16) short zt[2][DZc * GT];   // 2 x 16 KB

    const int tid  = threadIdx.x;
    const int lane = tid & 63;
    const int wid  = tid >> 6;
    const int wt = wid >> 1;          // 0..3 t-stripe
    const int wd = wid & 1;           // 0..1 d-half
    const int hi = lane >> 4;
    const int lm = lane & 15;

    // XCD swizzle: consecutive 32-block groups per XCD -> one b per pair of XCDs
    const int lb = ((blockIdx.x & 7) << 5) | (blockIdx.x >> 3);
    const int b  = lb >> 6;
    const int t0 = (lb & 63) << 6;

    float a00, a01, a10, a11;
    {
        const float LOG2E = 1.4426950408889634f;
        float c[2][2];
#pragma unroll
        for (int d = 0; d < 2; ++d)
#pragma unroll
            for (int k = 0; k < 2; ++k) {
                float p  = lsp[d * 2 + k];
                float sp = fmaxf(p, 0.0f) + log1pf(__expf(-fabsf(p)));
                float ls = 1e-5f + sp;
                c[d][k]  = -0.5f * LOG2E / (ls * ls);
            }
        a00 = c[0][0]; a01 = c[0][1]; a10 = c[1][0]; a11 = c[1][1];
    }

    const int t = t0 + wt * 16 + lm;
    const float2 xtv = *(const float2*)&xt[((long)b * NTt + t) * 2];

    f32x4 acc[4][2];
#pragma unroll
    for (int db = 0; db < 4; ++db)
#pragma unroll
        for (int k = 0; k < 2; ++k) acc[db][k] = (f32x4){0.f, 0.f, 0.f, 0.f};

    const char* imgb = (const char*)zimg + (long)b * NCH * IMG_CHUNK_B;

    auto stage = [&](int c, int buf) {
        const char* src = imgb + (long)c * IMG_CHUNK_B + tid * 16;
        char* dst = (char*)&zt[buf][0] + tid * 16;
        gload16(src, dst);
        gload16(src + 8192, dst + 8192);
    };

    stage(0, 0);
    __syncthreads();

    for (int c = 0; c < NCH; ++c) {
        const int cur = c & 1, nxt = cur ^ 1;
        if (c + 1 < NCH) stage(c + 1, nxt);
        const char* ztb = (const char*)&zt[cur][0];
#pragma unroll
        for (int kk = 0; kk < 2; ++kk) {
            bf16x8 Bf[4];
#pragma unroll
            for (int db = 0; db < 4; ++db) {
                int d = wd * 64 + db * 16 + lm;
                int byo = d * 128 + kk * 64 + hi * 16;
                byo ^= ((byo >> 9) & 1) << 5;          // st_16x32 read swizzle
                Bf[db] = *(const bf16x8*)(ztb + byo);
            }
            const int g0 = c * GT + kk * 32 + hi * 8;
            const float4* xp = (const float4*)(xgrid + ((long)b * NG + g0) * 2);
            float4 x0 = xp[0], x1 = xp[1], x2 = xp[2], x3 = xp[3];
            float gx[8] = {x0.x, x0.z, x1.x, x1.z, x2.x, x2.z, x3.x, x3.z};
            float gy[8] = {x0.y, x0.w, x1.y, x1.w, x2.y, x2.w, x3.y, x3.w};
            bf16x8 A0, A1;
#pragma unroll
            for (int j = 0; j < 8; ++j) {
                float dx = xtv.x - gx[j];
                float dy = xtv.y - gy[j];
                float s0 = dx * dx, s1 = dy * dy;
                A0[j] = f2bf(exp2f(s0 * a00 + s1 * a10));
                A1[j] = f2bf(exp2f(s0 * a01 + s1 * a11));
            }
#pragma unroll
            for (int db = 0; db < 4; ++db) {
                acc[db][0] = __builtin_amdgcn_mfma_f32_16x16x32_bf16(A0, Bf[db], acc[db][0], 0, 0, 0);
                acc[db][1] = __builtin_amdgcn_mfma_f32_16x16x32_bf16(A1, Bf[db], acc[db][1], 0, 0, 0);
            }
        }
        __syncthreads();
    }

#pragma unroll
    for (int db = 0; db < 4; ++db) {
        const int d = wd * 64 + db * 16 + lm;
#pragma unroll
        for (int r = 0; r < 4; ++r) {
            const int tt = t0 + wt * 16 + hi * 4 + r;
            float2 v = {acc[db][0][r], acc[db][1][r]};
            *(float2*)&out[(((long)b * NTt + tt) * DZc + d) * NKc] = v;
        }
    }
}

// ---------------------------------------------------------------------------
// Fallback (R1 kernel, known good at 154-176us) if ws is too small.
// ---------------------------------------------------------------------------
__global__ __launch_bounds__(256, 1)
void setconv_fused(const float* __restrict__ xgrid, const float* __restrict__ zgrid,
                   const float* __restrict__ xt, const float* __restrict__ lsp,
                   float* __restrict__ out)
{
    __shared__ __align__(16) short zt[2][DZc * 32];
    __shared__ __align__(16) float xgf[2][32 * 2];

    const int tid  = threadIdx.x;
    const int lane = tid & 63;
    const int wid  = tid >> 6;
    const int wt = wid >> 1;
    const int wd = wid & 1;
    const int hi = lane >> 4;
    const int lm = lane & 15;

    const int lb = ((blockIdx.x & 7) << 5) | (blockIdx.x >> 3);
    const int b  = lb >> 6;
    const int t0 = (lb & 63) << 6;

    float a00, a01, a10, a11;
    {
        const float LOG2E = 1.4426950408889634f;
        float c[2][2];
#pragma unroll
        for (int d = 0; d < 2; ++d)
#pragma unroll
            for (int k = 0; k < 2; ++k) {
                float p  = lsp[d * 2 + k];
                float sp = fmaxf(p, 0.0f) + log1pf(__expf(-fabsf(p)));
                float ls = 1e-5f + sp;
                c[d][k]  = -0.5f * LOG2E / (ls * ls);
            }
        a00 = c[0][0]; a01 = c[0][1]; a10 = c[1][0]; a11 = c[1][1];
    }

    float xtx[2], xty[2];
#pragma unroll
    for (int ts = 0; ts < 2; ++ts) {
        int t = t0 + wt * 32 + ts * 16 + lm;
        const float* p = &xt[((long)b * NTt + t) * 2];
        xtx[ts] = p[0]; xty[ts] = p[1];
    }

    f32x4 acc[2][4][2];
#pragma unroll
    for (int ts = 0; ts < 2; ++ts)
#pragma unroll
        for (int db = 0; db < 4; ++db)
#pragma unroll
            for (int k = 0; k < 2; ++k)
                acc[ts][db][k] = (f32x4){0.f, 0.f, 0.f, 0.f};

    const int dcol = tid & 127;
    const int g8a  = tid >> 7;
    const long zbase = (long)b * NG * DZc;
    const int swz = (dcol >> 1) & 3;
    const int soff0 = dcol * 32 + ((g8a       ^ swz) * 8);
    const int soff1 = dcol * 32 + (((g8a + 2) ^ swz) * 8);

    float zv[16];
    float xgv = 0.f;

    auto stage_load = [&](int c) {
        const int g0 = c * 32;
        const float* zc0 = zgrid + zbase + (long)(g0 + g8a * 8) * DZc + dcol;
        const float* zc1 = zgrid + zbase + (long)(g0 + (g8a + 2) * 8) * DZc + dcol;
#pragma unroll
        for (int j = 0; j < 8; ++j) zv[j] = zc0[j * DZc];
#pragma unroll
        for (int j = 0; j < 8; ++j) zv[8 + j] = zc1[j * DZc];
        if (wid == 0) xgv = xgrid[((long)b * NG + g0) * 2 + tid];
    };

    auto stage_store = [&](int buf) {
        bf16x8 p0, p1;
#pragma unroll
        for (int j = 0; j < 8; ++j) { p0[j] = f2bf(zv[j]); p1[j] = f2bf(zv[8 + j]); }
        *(bf16x8*)&zt[buf][soff0] = p0;
        *(bf16x8*)&zt[buf][soff1] = p1;
        if (wid == 0) xgf[buf][tid] = xgv;
    };

    auto compute = [&](int buf) {
        bf16x8 Bf[4];
#pragma unroll
        for (int db = 0; db < 4; ++db) {
            const int d = wd * 64 + db * 16 + lm;
            const short* zb = &zt[buf][d * 32];
            const int q = hi ^ (lm & 6);
            short4v lo = *(const short4v*)(zb + q * 4);
            short4v hh = *(const short4v*)(zb + (q ^ 4) * 4);
            Bf[db] = (bf16x8){lo.x, lo.y, lo.z, lo.w, hh.x, hh.y, hh.z, hh.w};
        }
        const float4* xp  = (const float4*)&xgf[buf][hi * 8];
        const float4* xp2 = (const float4*)&xgf[buf][32 + hi * 8];
        float4 x01 = xp[0],  x23 = xp[1];
        float4 x45 = xp2[0], x67 = xp2[1];
        float gx[8] = {x01.x, x01.z, x23.x, x23.z, x45.x, x45.z, x67.x, x67.z};
        float gy[8] = {x01.y, x01.w, x23.y, x23.w, x45.y, x45.w, x67.y, x67.w};
#pragma unroll
        for (int ts = 0; ts < 2; ++ts) {
            bf16x8 A0, A1;
#pragma unroll
            for (int j = 0; j < 8; ++j) {
                float dx = xtx[ts] - gx[j];
                float dy = xty[ts] - gy[j];
                float s0 = dx * dx, s1 = dy * dy;
                A0[j] = f2bf(exp2f(s0 * a00 + s1 * a10));
                A1[j] = f2bf(exp2f(s0 * a01 + s1 * a11));
            }
#pragma unroll
            for (int db = 0; db < 4; ++db) {
                acc[ts][db][0] = __builtin_amdgcn_mfma_f32_16x16x32_bf16(A0, Bf[db], acc[ts][db][0], 0, 0, 0);
                acc[ts][db][1] = __builtin_amdgcn_mfma_f32_16x16x32_bf16(A1, Bf[db], acc[ts][db][1], 0, 0, 0);
            }
        }
    };

    stage_load(0);
    stage_store(0);
    __syncthreads();

    for (int c = 0; c < NG / 32; ++c) {
        const int cur = c & 1;
        const int nxt = cur ^ 1;
        if (c + 1 < NG / 32) stage_load(c + 1);
        compute(cur);
        if (c + 1 < NG / 32) stage_store(nxt);
        __syncthreads();
    }

#pragma unroll
    for (int ts = 0; ts < 2; ++ts)
#pragma unroll
        for (int db = 0; db < 4; ++db) {
            const int d = wd * 64 + db * 16 + lm;
#pragma unroll
            for (int r = 0; r < 4; ++r) {
                const int t = t0 + wt * 32 + ts * 16 + hi * 4 + r;
                float2 v = {acc[ts][db][0][r], acc[ts][db][1][r]};
                *(float2*)&out[((long)(b * NTt + t) * DZc + d) * NKc] = v;
            }
        }
}

extern "C" void kernel_launch(void* const* d_in, const int* in_sizes, int n_in,
                              void* d_out, int out_size, void* d_ws, size_t ws_size,
                              hipStream_t stream) {
    const float* xg  = (const float*)d_in[0];   // x_grid [4,64,64,2]
    const float* zg  = (const float*)d_in[1];   // z_grid [4,64,64,128]
    const float* xtp = (const float*)d_in[2];   // xt     [4,4096,2]
    const float* ls  = (const float*)d_in[3];   // lengthscale_param [2,2]
    float* o = (float*)d_out;                   // [4,4096,256] fp32

    if (ws_size >= (size_t)IMG_BYTES) {
        short* img = (short*)d_ws;
        hipLaunchKernelGGL(zcvt_kernel, dim3(4 * NCH), dim3(256), 0, stream, zg, img);
        hipLaunchKernelGGL(setconv_main, dim3(256), dim3(512), 0, stream, xg, xtp, ls, img, o);
    } else {
        hipLaunchKernelGGL(setconv_fused, dim3(256), dim3(256), 0, stream, xg, zg, xtp, ls, o);
    }
}

// Round 3
// 73.838 us; speedup vs baseline: 2.0857x; 1.8670x over previous
//
#include <hip/hip_runtime.h>
#include <hip/hip_bf16.h>

namespace {
constexpr int NG  = 4096;   // grid points per batch
constexpr int NTt = 4096;   // target points
constexpr int DZc = 128;
constexpr int NKc = 2;
constexpr int GT  = 64;     // g per chunk
constexpr int NCH = NG / GT;                              // 64 chunks
constexpr long IMG_CHUNK_B = (long)DZc * GT * 2;          // 16384 B per chunk image
constexpr long IMG_BYTES   = 4L * NCH * IMG_CHUNK_B;      // 4.19 MB

typedef __attribute__((ext_vector_type(8))) short bf16x8;
typedef __attribute__((ext_vector_type(4))) float f32x4;

__device__ __forceinline__ short f2bf(float x) {
    __hip_bfloat16 h = __float2bfloat16(x);
    return __builtin_bit_cast(short, h);
}

__device__ __forceinline__ void gload16(const void* g, void* lds) {
    __builtin_amdgcn_global_load_lds(
        (const __attribute__((address_space(1))) void*)g,
        (__attribute__((address_space(3))) void*)lds, 16, 0, 0);
}
}

// ---------------------------------------------------------------------------
// Pre-kernel: z fp32 [b][g][128] -> bf16 chunk images in ws.
// Image chunk (b,c): 128 d-rows x 64 g-slots bf16 (row = 128 B).
// Swizzle: physical byte y holds logical byte y ^ (((y>>7)&7)<<4)
// (G4: row&7 XOR'd into the 16B-slot index; involution since bits 4-6 only).
// logical l = d*128 + s*2, value = z[b][c*64+s][d].
// ---------------------------------------------------------------------------
__global__ __launch_bounds__(256)
void zcvt_kernel(const float* __restrict__ zg, short* __restrict__ img)
{
    __shared__ float tile[GT * DZc];   // [s][d] fp32, 32 KB
    const int tid = threadIdx.x;
    const int blk = blockIdx.x;        // 256 = 4 b x 64 c
    const int c = blk & 63, b = blk >> 6;
    const float* zb = zg + ((long)(b * NG + c * GT)) * DZc;
#pragma unroll
    for (int it = 0; it < 8; ++it) {
        int f = tid + it * 256;        // 2048 float4 tiles
        int s = f >> 5, dq = f & 31;
        float4 v = *(const float4*)(zb + (long)s * DZc + dq * 4);
        *(float4*)&tile[s * DZc + dq * 4] = v;
    }
    __syncthreads();
    char* ib = (char*)img + (long)blk * IMG_CHUNK_B;
#pragma unroll
    for (int it = 0; it < 4; ++it) {
        int p = tid + it * 256;        // 16B block id 0..1023
        int y = p * 16;
        int l = y ^ (((y >> 7) & 7) << 4);   // inverse of read swizzle
        int d  = l >> 7;
        int s0 = (l >> 1) & 63;
        bf16x8 o;
#pragma unroll
        for (int j = 0; j < 8; ++j) o[j] = f2bf(tile[(s0 + j) * DZc + d]);
        *(bf16x8*)(ib + y) = o;
    }
}

// ---------------------------------------------------------------------------
// Main kernel: 256 blocks (b, 64t-tile) x 512 threads = 8 waves.
// Wave (wt, ws): t-stripe wt (16 t), FULL 128 d, K-half ws (g-chunks
// ws*32..ws*32+31). Split-K removes the A-gen redundancy (R=2 -> R=1).
// LDS: 2 K-half regions x 2 dbuf x 16 KB = 64 KB; reused for the f32x2
// partial-C reduction at the end.
// ---------------------------------------------------------------------------
__global__ __launch_bounds__(512, 2)
void setconv_main(const float* __restrict__ xgrid, const float* __restrict__ xt,
                  const float* __restrict__ lsp, const short* __restrict__ zimg,
                  float* __restrict__ out)
{
    __shared__ __align__(16) char lds[65536];

    const int tid  = threadIdx.x;
    const int lane = tid & 63;
    const int wid  = tid >> 6;
    const int wt = wid >> 1;          // 0..3 t-stripe
    const int ws = wid & 1;           // K-half
    const int hi = lane >> 4;
    const int lm = lane & 15;

    // XCD swizzle: 32 consecutive blocks per XCD -> one b per XCD pair
    const int lb = ((blockIdx.x & 7) << 5) | (blockIdx.x >> 3);
    const int b  = lb >> 6;
    const int t0 = (lb & 63) << 6;

    float a00, a01, a10, a11;
    {
        const float LOG2E = 1.4426950408889634f;
        float cf[2][2];
#pragma unroll
        for (int d = 0; d < 2; ++d)
#pragma unroll
            for (int k = 0; k < 2; ++k) {
                float p  = lsp[d * 2 + k];
                float sp = fmaxf(p, 0.0f) + log1pf(__expf(-fabsf(p)));
                float ls = 1e-5f + sp;
                cf[d][k] = -0.5f * LOG2E / (ls * ls);
            }
        a00 = cf[0][0]; a01 = cf[0][1]; a10 = cf[1][0]; a11 = cf[1][1];
    }

    const int t = t0 + wt * 16 + lm;
    const float2 xtv = *(const float2*)&xt[((long)b * NTt + t) * 2];

    f32x4 acc[8][2];
#pragma unroll
    for (int db = 0; db < 8; ++db)
#pragma unroll
        for (int k = 0; k < 2; ++k) acc[db][k] = (f32x4){0.f, 0.f, 0.f, 0.f};

    const char* imgb = (const char*)zimg + (long)b * NCH * IMG_CHUNK_B;

    // stage chunk c0 -> half0 buf, chunk c1 -> half1 buf (linear dest, tid*16)
    auto stage = [&](int c0, int c1, int buf) {
        const char* s0 = imgb + (long)c0 * IMG_CHUNK_B + tid * 16;
        const char* s1 = imgb + (long)c1 * IMG_CHUNK_B + tid * 16;
        char* d0 = lds + buf * 16384 + tid * 16;
        char* d1 = lds + 32768 + buf * 16384 + tid * 16;
        gload16(s0, d0);
        gload16(s0 + 8192, d0 + 8192);
        gload16(s1, d1);
        gload16(s1 + 8192, d1 + 8192);
    };

    stage(0, 32, 0);
    __syncthreads();

    const char* myhalf = lds + ws * 32768;
    // per-lane swizzled 16B-slot offsets for kk=0/1 (row bits unaffected)
    const int o_kk0 = lm * 128 + (((0 * 4 + hi) ^ (lm & 7)) << 4);
    const int o_kk1 = lm * 128 + (((1 * 4 + hi) ^ (lm & 7)) << 4);

    for (int i = 0; i < 32; ++i) {
        const int cur = i & 1, nxt = cur ^ 1;
        if (i + 1 < 32) stage(i + 1, 33 + i, nxt);
        const int c = ws * 32 + i;
        const char* ztb = myhalf + cur * 16384;
#pragma unroll
        for (int kk = 0; kk < 2; ++kk) {
            const char* rbase = ztb + (kk ? o_kk1 : o_kk0);
            bf16x8 Bf[8];
#pragma unroll
            for (int db = 0; db < 8; ++db)
                Bf[db] = *(const bf16x8*)(rbase + db * 2048);
            const int g0 = c * GT + kk * 32 + hi * 8;
            const float4* xp = (const float4*)(xgrid + ((long)b * NG + g0) * 2);
            float4 x0 = xp[0], x1 = xp[1], x2 = xp[2], x3 = xp[3];
            float gx[8] = {x0.x, x0.z, x1.x, x1.z, x2.x, x2.z, x3.x, x3.z};
            float gy[8] = {x0.y, x0.w, x1.y, x1.w, x2.y, x2.w, x3.y, x3.w};
            bf16x8 A0, A1;
#pragma unroll
            for (int j = 0; j < 8; ++j) {
                float dx = xtv.x - gx[j];
                float dy = xtv.y - gy[j];
                float s0 = dx * dx, s1 = dy * dy;
                A0[j] = f2bf(__builtin_amdgcn_exp2f(s0 * a00 + s1 * a10));
                A1[j] = f2bf(__builtin_amdgcn_exp2f(s0 * a01 + s1 * a11));
            }
#pragma unroll
            for (int db = 0; db < 8; ++db) {
                acc[db][0] = __builtin_amdgcn_mfma_f32_16x16x32_bf16(A0, Bf[db], acc[db][0], 0, 0, 0);
                acc[db][1] = __builtin_amdgcn_mfma_f32_16x16x32_bf16(A1, Bf[db], acc[db][1], 0, 0, 0);
            }
        }
        __syncthreads();
    }

    // -------- split-K reduction through LDS (conflict-free b64) --------
    // area[wt][db][row(16)][lm(16)] of float2 = 64 KB, reuses staging LDS.
    float2* area = (float2*)lds;
    if (ws == 0) {
#pragma unroll
        for (int db = 0; db < 8; ++db)
#pragma unroll
            for (int r = 0; r < 4; ++r) {
                const int row = hi * 4 + r;
                area[((wt * 8 + db) * 16 + row) * 16 + lm] =
                    (float2){acc[db][0][r], acc[db][1][r]};
            }
    }
    __syncthreads();
    if (ws == 1) {
#pragma unroll
        for (int db = 0; db < 8; ++db) {
            const int d = db * 16 + lm;
#pragma unroll
            for (int r = 0; r < 4; ++r) {
                const int row = hi * 4 + r;
                float2 v = area[((wt * 8 + db) * 16 + row) * 16 + lm];
                const int tt = t0 + wt * 16 + row;
                float2 o = {acc[db][0][r] + v.x, acc[db][1][r] + v.y};
                *(float2*)&out[(((long)b * NTt + tt) * DZc + d) * NKc] = o;
            }
        }
    }
}

// ---------------------------------------------------------------------------
// Fallback (R1 kernel, known good) if ws is too small.
// ---------------------------------------------------------------------------
__global__ __launch_bounds__(256, 1)
void setconv_fused(const float* __restrict__ xgrid, const float* __restrict__ zgrid,
                   const float* __restrict__ xt, const float* __restrict__ lsp,
                   float* __restrict__ out)
{
    __shared__ __align__(16) short zt[2][DZc * 32];
    __shared__ __align__(16) float xgf[2][32 * 2];

    const int tid  = threadIdx.x;
    const int lane = tid & 63;
    const int wid  = tid >> 6;
    const int wt = wid >> 1;
    const int wd = wid & 1;
    const int hi = lane >> 4;
    const int lm = lane & 15;

    const int lb = ((blockIdx.x & 7) << 5) | (blockIdx.x >> 3);
    const int b  = lb >> 6;
    const int t0 = (lb & 63) << 6;

    float a00, a01, a10, a11;
    {
        const float LOG2E = 1.4426950408889634f;
        float cf[2][2];
#pragma unroll
        for (int d = 0; d < 2; ++d)
#pragma unroll
            for (int k = 0; k < 2; ++k) {
                float p  = lsp[d * 2 + k];
                float sp = fmaxf(p, 0.0f) + log1pf(__expf(-fabsf(p)));
                float ls = 1e-5f + sp;
                cf[d][k] = -0.5f * LOG2E / (ls * ls);
            }
        a00 = cf[0][0]; a01 = cf[0][1]; a10 = cf[1][0]; a11 = cf[1][1];
    }

    float xtx[2], xty[2];
#pragma unroll
    for (int ts = 0; ts < 2; ++ts) {
        int t = t0 + wt * 32 + ts * 16 + lm;
        const float* p = &xt[((long)b * NTt + t) * 2];
        xtx[ts] = p[0]; xty[ts] = p[1];
    }

    f32x4 acc[2][4][2];
#pragma unroll
    for (int ts = 0; ts < 2; ++ts)
#pragma unroll
        for (int db = 0; db < 4; ++db)
#pragma unroll
            for (int k = 0; k < 2; ++k)
                acc[ts][db][k] = (f32x4){0.f, 0.f, 0.f, 0.f};

    const int dcol = tid & 127;
    const int g8a  = tid >> 7;
    const long zbase = (long)b * NG * DZc;
    const int swz = (dcol >> 1) & 3;
    const int soff0 = dcol * 32 + ((g8a       ^ swz) * 8);
    const int soff1 = dcol * 32 + (((g8a + 2) ^ swz) * 8);

    float zv[16];
    float xgv = 0.f;

    auto stage_load = [&](int c) {
        const int g0 = c * 32;
        const float* zc0 = zgrid + zbase + (long)(g0 + g8a * 8) * DZc + dcol;
        const float* zc1 = zgrid + zbase + (long)(g0 + (g8a + 2) * 8) * DZc + dcol;
#pragma unroll
        for (int j = 0; j < 8; ++j) zv[j] = zc0[j * DZc];
#pragma unroll
        for (int j = 0; j < 8; ++j) zv[8 + j] = zc1[j * DZc];
        if (wid == 0) xgv = xgrid[((long)b * NG + g0) * 2 + tid];
    };

    auto stage_store = [&](int buf) {
        bf16x8 p0, p1;
#pragma unroll
        for (int j = 0; j < 8; ++j) { p0[j] = f2bf(zv[j]); p1[j] = f2bf(zv[8 + j]); }
        *(bf16x8*)&zt[buf][soff0] = p0;
        *(bf16x8*)&zt[buf][soff1] = p1;
        if (wid == 0) xgf[buf][tid] = xgv;
    };

    auto compute = [&](int buf) {
        typedef __attribute__((ext_vector_type(4))) short short4v;
        bf16x8 Bf[4];
#pragma unroll
        for (int db = 0; db < 4; ++db) {
            const int d = wd * 64 + db * 16 + lm;
            const short* zb = &zt[buf][d * 32];
            const int q = hi ^ (lm & 6);
            short4v lo = *(const short4v*)(zb + q * 4);
            short4v hh = *(const short4v*)(zb + (q ^ 4) * 4);
            Bf[db] = (bf16x8){lo.x, lo.y, lo.z, lo.w, hh.x, hh.y, hh.z, hh.w};
        }
        const float4* xp  = (const float4*)&xgf[buf][hi * 8];
        const float4* xp2 = (const float4*)&xgf[buf][32 + hi * 8];
        float4 x01 = xp[0],  x23 = xp[1];
        float4 x45 = xp2[0], x67 = xp2[1];
        float gx[8] = {x01.x, x01.z, x23.x, x23.z, x45.x, x45.z, x67.x, x67.z};
        float gy[8] = {x01.y, x01.w, x23.y, x23.w, x45.y, x45.w, x67.y, x67.w};
#pragma unroll
        for (int ts = 0; ts < 2; ++ts) {
            bf16x8 A0, A1;
#pragma unroll
            for (int j = 0; j < 8; ++j) {
                float dx = xtx[ts] - gx[j];
                float dy = xty[ts] - gy[j];
                float s0 = dx * dx, s1 = dy * dy;
                A0[j] = f2bf(__builtin_amdgcn_exp2f(s0 * a00 + s1 * a10));
                A1[j] = f2bf(__builtin_amdgcn_exp2f(s0 * a01 + s1 * a11));
            }
#pragma unroll
            for (int db = 0; db < 4; ++db) {
                acc[ts][db][0] = __builtin_amdgcn_mfma_f32_16x16x32_bf16(A0, Bf[db], acc[ts][db][0], 0, 0, 0);
                acc[ts][db][1] = __builtin_amdgcn_mfma_f32_16x16x32_bf16(A1, Bf[db], acc[ts][db][1], 0, 0, 0);
            }
        }
    };

    stage_load(0);
    stage_store(0);
    __syncthreads();

    for (int c = 0; c < NG / 32; ++c) {
        const int cur = c & 1;
        const int nxt = cur ^ 1;
        if (c + 1 < NG / 32) stage_load(c + 1);
        compute(cur);
        if (c + 1 < NG / 32) stage_store(nxt);
        __syncthreads();
    }

#pragma unroll
    for (int ts = 0; ts < 2; ++ts)
#pragma unroll
        for (int db = 0; db < 4; ++db) {
            const int d = wd * 64 + db * 16 + lm;
#pragma unroll
            for (int r = 0; r < 4; ++r) {
                const int t = t0 + wt * 32 + ts * 16 + hi * 4 + r;
                float2 v = {acc[ts][db][0][r], acc[ts][db][1][r]};
                *(float2*)&out[((long)(b * NTt + t) * DZc + d) * NKc] = v;
            }
        }
}

extern "C" void kernel_launch(void* const* d_in, const int* in_sizes, int n_in,
                              void* d_out, int out_size, void* d_ws, size_t ws_size,
                              hipStream_t stream) {
    const float* xg  = (const float*)d_in[0];   // x_grid [4,64,64,2]
    const float* zg  = (const float*)d_in[1];   // z_grid [4,64,64,128]
    const float* xtp = (const float*)d_in[2];   // xt     [4,4096,2]
    const float* ls  = (const float*)d_in[3];   // lengthscale_param [2,2]
    float* o = (float*)d_out;                   // [4,4096,256] fp32

    if (ws_size >= (size_t)IMG_BYTES) {
        short* img = (short*)d_ws;
        hipLaunchKernelGGL(zcvt_kernel, dim3(4 * NCH), dim3(256), 0, stream, zg, img);
        hipLaunchKernelGGL(setconv_main, dim3(256), dim3(512), 0, stream, xg, xtp, ls, img, o);
    } else {
        hipLaunchKernelGGL(setconv_fused, dim3(256), dim3(256), 0, stream, xg, zg, xtp, ls, o);
    }
}

// Round 5
// 66.739 us; speedup vs baseline: 2.3076x; 1.1064x over previous
//
#include <hip/hip_runtime.h>
#include <hip/hip_bf16.h>

namespace {
constexpr int NG  = 4096;   // grid points per batch
constexpr int NTt = 4096;   // target points
constexpr int DZc = 128;
constexpr int NKc = 2;
constexpr int GT  = 32;     // g per chunk (one MFMA-K)
constexpr int NCH = NG / GT;                              // 128 chunks per b
constexpr long CHUNK_B   = (long)DZc * GT * 2;            // 8192 B per chunk
constexpr long IMG_BYTES = 4L * NCH * CHUNK_B;            // 4.19 MB

typedef __attribute__((ext_vector_type(8))) short bf16x8;
typedef __attribute__((ext_vector_type(4))) float f32x4;

__device__ __forceinline__ short f2bf(float x) {
    __hip_bfloat16 h = __float2bfloat16(x);
    return __builtin_bit_cast(short, h);
}

__device__ __forceinline__ void gload16(const void* g, void* lds) {
    __builtin_amdgcn_global_load_lds(
        (const __attribute__((address_space(1))) void*)g,
        (__attribute__((address_space(3))) void*)lds, 16, 0, 0);
}
}

// ---------------------------------------------------------------------------
// Pre-kernel: z fp32 [b][g][128] -> bf16 chunk images (8 KB / 32 g) in ws.
// Chunk c physical 16B-block p: d = p>>2, ps = p&3. Logical slot
// s = ps ^ ((d>>1)&3), g = c*32 + s*8 + j, value = bf16(z[b][g][d]).
// ---------------------------------------------------------------------------
__global__ __launch_bounds__(256)
void zcvt_kernel(const float* __restrict__ zg, short* __restrict__ img)
{
    __shared__ __align__(16) float tile[GT * 132];   // [s][d] fp32, row pad->132
    const int tid = threadIdx.x;
    const int blk = blockIdx.x;        // 512 = 4 b x 128 c
    const int c = blk & 127, b = blk >> 7;
    const float* zb = zg + ((long)(b * NG + c * GT)) * DZc;
#pragma unroll
    for (int it = 0; it < 4; ++it) {
        int f = tid + it * 256;        // 1024 float4 tiles
        int s = f >> 5, dq = f & 31;
        float4 v = *(const float4*)(zb + (long)s * DZc + dq * 4);
        *(float4*)&tile[s * 132 + dq * 4] = v;
    }
    __syncthreads();
    char* ib = (char*)img + (long)blk * CHUNK_B;
#pragma unroll
    for (int it = 0; it < 2; ++it) {
        int p = tid + it * 256;        // 16B block id 0..511
        int y = p * 16;
        int d  = p >> 2;
        int ps = p & 3;
        int s8 = (ps ^ ((d >> 1) & 3)) * 8;
        bf16x8 o;
#pragma unroll
        for (int j = 0; j < 8; ++j) o[j] = f2bf(tile[(s8 + j) * 132 + d]);
        *(bf16x8*)(ib + y) = o;
    }
}

// ---------------------------------------------------------------------------
// Main kernel: 512 blocks (b, 32t-tile) x 512 threads = 8 waves (2 wt x 4 ws).
// Wave (wt, ws): 16 t x FULL 128 d, K-quarter ws (chunks ws*32..ws*32+31).
// LDS: 4 K-regions x 2 dbuf x 8 KB = 64 KB -> 2 blocks/CU = 4 waves/SIMD.
// Split-K tree reduction: ws1->ws0 & ws3->ws2 (64 KB), then ws2->ws0 (32 KB).
// ---------------------------------------------------------------------------
__global__ __launch_bounds__(512, 4)
void setconv_main(const float* __restrict__ xgrid, const float* __restrict__ xt,
                  const float* __restrict__ lsp, const short* __restrict__ zimg,
                  float* __restrict__ out)
{
    __shared__ __align__(16) char lds[65536];

    const int tid  = threadIdx.x;
    const int lane = tid & 63;
    const int wid  = tid >> 6;
    const int wt = wid >> 2;          // 0..1 t-stripe
    const int ws = wid & 3;           // K-quarter
    const int hi = lane >> 4;
    const int lm = lane & 15;

    // XCD swizzle: 64 consecutive lb per XCD -> 2 XCDs per b (1 MB image in L2)
    const int lb = ((blockIdx.x & 7) << 6) | (blockIdx.x >> 3);
    const int b  = lb >> 7;
    const int t0 = (lb & 127) << 5;

    float a00, a01, a10, a11;
    {
        const float LOG2E = 1.4426950408889634f;
        float cf[2][2];
#pragma unroll
        for (int d = 0; d < 2; ++d)
#pragma unroll
            for (int k = 0; k < 2; ++k) {
                float p  = lsp[d * 2 + k];
                float sp = fmaxf(p, 0.0f) + log1pf(__expf(-fabsf(p)));
                float ls = 1e-5f + sp;
                cf[d][k] = -0.5f * LOG2E / (ls * ls);
            }
        a00 = cf[0][0]; a01 = cf[0][1]; a10 = cf[1][0]; a11 = cf[1][1];
    }

    const int t = t0 + wt * 16 + lm;
    const float2 xtv = *(const float2*)&xt[((long)b * NTt + t) * 2];

    f32x4 acc[8][2];
#pragma unroll
    for (int db = 0; db < 8; ++db)
#pragma unroll
        for (int k = 0; k < 2; ++k) acc[db][k] = (f32x4){0.f, 0.f, 0.f, 0.f};

    const char* imgb = (const char*)zimg + (long)b * NCH * CHUNK_B;

    // stage chunk (r*32 + i) -> region r, buffer buf, for all 4 regions
    auto stage = [&](int i, int buf) {
#pragma unroll
        for (int r = 0; r < 4; ++r) {
            const char* src = imgb + ((long)(r * 32 + i)) * CHUNK_B + tid * 16;
            char* dst = lds + r * 16384 + buf * 8192 + tid * 16;
            gload16(src, dst);
        }
    };

    stage(0, 0);
    __syncthreads();

    // per-lane swizzled read base within a chunk
    const int roff = lm * 64 + ((hi ^ ((lm >> 1) & 3)) << 4);
    const char* myreg = lds + ws * 16384;

    for (int i = 0; i < 32; ++i) {
        const int cur = i & 1, nxt = cur ^ 1;
        if (i + 1 < 32) stage(i + 1, nxt);
        const int c = ws * 32 + i;
        const char* rbase = myreg + cur * 8192 + roff;

        // A-gen: this lane's t-row vs g = c*32 + hi*8 + j
        const int g0 = c * GT + hi * 8;
        const float4* xp = (const float4*)(xgrid + ((long)b * NG + g0) * 2);
        float4 x0 = xp[0], x1 = xp[1], x2 = xp[2], x3 = xp[3];
        float gx[8] = {x0.x, x0.z, x1.x, x1.z, x2.x, x2.z, x3.x, x3.z};
        float gy[8] = {x0.y, x0.w, x1.y, x1.w, x2.y, x2.w, x3.y, x3.w};
        bf16x8 A0, A1;
#pragma unroll
        for (int j = 0; j < 8; ++j) {
            float dx = xtv.x - gx[j];
            float dy = xtv.y - gy[j];
            float s0 = dx * dx, s1 = dy * dy;
            A0[j] = f2bf(__builtin_amdgcn_exp2f(s0 * a00 + s1 * a10));
            A1[j] = f2bf(__builtin_amdgcn_exp2f(s0 * a01 + s1 * a11));
        }
#pragma unroll
        for (int db = 0; db < 8; ++db) {
            bf16x8 Bf = *(const bf16x8*)(rbase + db * 1024);
            acc[db][0] = __builtin_amdgcn_mfma_f32_16x16x32_bf16(A0, Bf, acc[db][0], 0, 0, 0);
            acc[db][1] = __builtin_amdgcn_mfma_f32_16x16x32_bf16(A1, Bf, acc[db][1], 0, 0, 0);
        }
        __syncthreads();
    }

    // -------- split-K tree reduction through LDS --------
    // Each partial = 8 db x 16 row x 16 lm float2 = 2048 f2 = 16 KB.
    // Phase A: ws 1,3 write -> slots (wt*2 + ws>>1), 4 x 16 KB = 64 KB; ws 0,2 add.
    // Phase B: ws 2 writes -> slot wt (32 KB); ws 0 adds + stores out.
    float2* area = (float2*)lds;
    const int slotA = wt * 2 + (ws >> 1);
    if (ws & 1) {
#pragma unroll
        for (int db = 0; db < 8; ++db)
#pragma unroll
            for (int r = 0; r < 4; ++r) {
                const int row = hi * 4 + r;
                area[slotA * 2048 + (db * 16 + row) * 16 + lm] =
                    (float2){acc[db][0][r], acc[db][1][r]};
            }
    }
    __syncthreads();
    if (!(ws & 1)) {
#pragma unroll
        for (int db = 0; db < 8; ++db)
#pragma unroll
            for (int r = 0; r < 4; ++r) {
                const int row = hi * 4 + r;
                float2 v = area[slotA * 2048 + (db * 16 + row) * 16 + lm];
                acc[db][0][r] += v.x;
                acc[db][1][r] += v.y;
            }
    }
    __syncthreads();
    if (ws == 2) {
#pragma unroll
        for (int db = 0; db < 8; ++db)
#pragma unroll
            for (int r = 0; r < 4; ++r) {
                const int row = hi * 4 + r;
                area[wt * 2048 + (db * 16 + row) * 16 + lm] =
                    (float2){acc[db][0][r], acc[db][1][r]};
            }
    }
    __syncthreads();
    if (ws == 0) {
#pragma unroll
        for (int db = 0; db < 8; ++db) {
            const int d = db * 16 + lm;
#pragma unroll
            for (int r = 0; r < 4; ++r) {
                const int row = hi * 4 + r;
                float2 v = area[wt * 2048 + (db * 16 + row) * 16 + lm];
                const int tt = t0 + wt * 16 + row;
                *(float2*)&out[(((long)b * NTt + tt) * DZc + d) * NKc] =
                    (float2){acc[db][0][r] + v.x, acc[db][1][r] + v.y};
            }
        }
    }
}

// ---------------------------------------------------------------------------
// Fallback (R1 kernel, known good) if ws is too small.
// ---------------------------------------------------------------------------
__global__ __launch_bounds__(256, 1)
void setconv_fused(const float* __restrict__ xgrid, const float* __restrict__ zgrid,
                   const float* __restrict__ xt, const float* __restrict__ lsp,
                   float* __restrict__ out)
{
    __shared__ __align__(16) short zt[2][DZc * 32];
    __shared__ __align__(16) float xgf[2][32 * 2];

    const int tid  = threadIdx.x;
    const int lane = tid & 63;
    const int wid  = tid >> 6;
    const int wt = wid >> 1;
    const int wd = wid & 1;
    const int hi = lane >> 4;
    const int lm = lane & 15;

    const int lb = ((blockIdx.x & 7) << 5) | (blockIdx.x >> 3);
    const int b  = lb >> 6;
    const int t0 = (lb & 63) << 6;

    float a00, a01, a10, a11;
    {
        const float LOG2E = 1.4426950408889634f;
        float cf[2][2];
#pragma unroll
        for (int d = 0; d < 2; ++d)
#pragma unroll
            for (int k = 0; k < 2; ++k) {
                float p  = lsp[d * 2 + k];
                float sp = fmaxf(p, 0.0f) + log1pf(__expf(-fabsf(p)));
                float ls = 1e-5f + sp;
                cf[d][k] = -0.5f * LOG2E / (ls * ls);
            }
        a00 = cf[0][0]; a01 = cf[0][1]; a10 = cf[1][0]; a11 = cf[1][1];
    }

    float xtx[2], xty[2];
#pragma unroll
    for (int ts = 0; ts < 2; ++ts) {
        int t = t0 + wt * 32 + ts * 16 + lm;
        const float* p = &xt[((long)b * NTt + t) * 2];
        xtx[ts] = p[0]; xty[ts] = p[1];
    }

    f32x4 acc[2][4][2];
#pragma unroll
    for (int ts = 0; ts < 2; ++ts)
#pragma unroll
        for (int db = 0; db < 4; ++db)
#pragma unroll
            for (int k = 0; k < 2; ++k)
                acc[ts][db][k] = (f32x4){0.f, 0.f, 0.f, 0.f};

    const int dcol = tid & 127;
    const int g8a  = tid >> 7;
    const long zbase = (long)b * NG * DZc;
    const int swz = (dcol >> 1) & 3;
    const int soff0 = dcol * 32 + ((g8a       ^ swz) * 8);
    const int soff1 = dcol * 32 + (((g8a + 2) ^ swz) * 8);

    float zv[16];
    float xgv = 0.f;

    auto stage_load = [&](int c) {
        const int g0 = c * 32;
        const float* zc0 = zgrid + zbase + (long)(g0 + g8a * 8) * DZc + dcol;
        const float* zc1 = zgrid + zbase + (long)(g0 + (g8a + 2) * 8) * DZc + dcol;
#pragma unroll
        for (int j = 0; j < 8; ++j) zv[j] = zc0[j * DZc];
#pragma unroll
        for (int j = 0; j < 8; ++j) zv[8 + j] = zc1[j * DZc];
        if (wid == 0) xgv = xgrid[((long)b * NG + g0) * 2 + tid];
    };

    auto stage_store = [&](int buf) {
        bf16x8 p0, p1;
#pragma unroll
        for (int j = 0; j < 8; ++j) { p0[j] = f2bf(zv[j]); p1[j] = f2bf(zv[8 + j]); }
        *(bf16x8*)&zt[buf][soff0] = p0;
        *(bf16x8*)&zt[buf][soff1] = p1;
        if (wid == 0) xgf[buf][tid] = xgv;
    };

    auto compute = [&](int buf) {
        typedef __attribute__((ext_vector_type(4))) short short4v;
        bf16x8 Bf[4];
#pragma unroll
        for (int db = 0; db < 4; ++db) {
            const int d = wd * 64 + db * 16 + lm;
            const short* zb = &zt[buf][d * 32];
            const int q = hi ^ (lm & 6);
            short4v lo = *(const short4v*)(zb + q * 4);
            short4v hh = *(const short4v*)(zb + (q ^ 4) * 4);
            Bf[db] = (bf16x8){lo.x, lo.y, lo.z, lo.w, hh.x, hh.y, hh.z, hh.w};
        }
        const float4* xp  = (const float4*)&xgf[buf][hi * 8];
        const float4* xp2 = (const float4*)&xgf[buf][32 + hi * 8];
        float4 x01 = xp[0],  x23 = xp[1];
        float4 x45 = xp2[0], x67 = xp2[1];
        float gx[8] = {x01.x, x01.z, x23.x, x23.z, x45.x, x45.z, x67.x, x67.z};
        float gy[8] = {x01.y, x01.w, x23.y, x23.w, x45.y, x45.w, x67.y, x67.w};
#pragma unroll
        for (int ts = 0; ts < 2; ++ts) {
            bf16x8 A0, A1;
#pragma unroll
            for (int j = 0; j < 8; ++j) {
                float dx = xtx[ts] - gx[j];
                float dy = xty[ts] - gy[j];
                float s0 = dx * dx, s1 = dy * dy;
                A0[j] = f2bf(__builtin_amdgcn_exp2f(s0 * a00 + s1 * a10));
                A1[j] = f2bf(__builtin_amdgcn_exp2f(s0 * a01 + s1 * a11));
            }
#pragma unroll
            for (int db = 0; db < 4; ++db) {
                acc[ts][db][0] = __builtin_amdgcn_mfma_f32_16x16x32_bf16(A0, Bf[db], acc[ts][db][0], 0, 0, 0);
                acc[ts][db][1] = __builtin_amdgcn_mfma_f32_16x16x32_bf16(A1, Bf[db], acc[ts][db][1], 0, 0, 0);
            }
        }
    };

    stage_load(0);
    stage_store(0);
    __syncthreads();

    for (int c = 0; c < NG / 32; ++c) {
        const int cur = c & 1;
        const int nxt = cur ^ 1;
        if (c + 1 < NG / 32) stage_load(c + 1);
        compute(cur);
        if (c + 1 < NG / 32) stage_store(nxt);
        __syncthreads();
    }

#pragma unroll
    for (int ts = 0; ts < 2; ++ts)
#pragma unroll
        for (int db = 0; db < 4; ++db) {
            const int d = wd * 64 + db * 16 + lm;
#pragma unroll
            for (int r = 0; r < 4; ++r) {
                const int t = t0 + wt * 32 + ts * 16 + hi * 4 + r;
                float2 v = {acc[ts][db][0][r], acc[ts][db][1][r]};
                *(float2*)&out[((long)(b * NTt + t) * DZc + d) * NKc] = v;
            }
        }
}

extern "C" void kernel_launch(void* const* d_in, const int* in_sizes, int n_in,
                              void* d_out, int out_size, void* d_ws, size_t ws_size,
                              hipStream_t stream) {
    const float* xg  = (const float*)d_in[0];   // x_grid [4,64,64,2]
    const float* zg  = (const float*)d_in[1];   // z_grid [4,64,64,128]
    const float* xtp = (const float*)d_in[2];   // xt     [4,4096,2]
    const float* ls  = (const float*)d_in[3];   // lengthscale_param [2,2]
    float* o = (float*)d_out;                   // [4,4096,256] fp32

    if (ws_size >= (size_t)IMG_BYTES) {
        short* img = (short*)d_ws;
        hipLaunchKernelGGL(zcvt_kernel, dim3(512), dim3(256), 0, stream, zg, img);
        hipLaunchKernelGGL(setconv_main, dim3(512), dim3(512), 0, stream, xg, xtp, ls, img, o);
    } else {
        hipLaunchKernelGGL(setconv_fused, dim3(256), dim3(256), 0, stream, xg, zg, xtp, ls, o);
    }
}

// Round 8
// 61.536 us; speedup vs baseline: 2.5027x; 1.0846x over previous
//
#include <hip/hip_runtime.h>
#include <hip/hip_bf16.h>

namespace {
constexpr int NG  = 4096;   // grid points per batch
constexpr int NTt = 4096;   // target points
constexpr int DZc = 128;
constexpr int NKc = 2;
constexpr int GT  = 32;     // g per chunk (one MFMA-K)
constexpr int NCH = NG / GT;                              // 128 chunks per b
constexpr long CHUNK_B   = (long)DZc * GT * 2;            // 8192 B per chunk
constexpr long IMG_BYTES = 4L * NCH * CHUNK_B;            // 4.19 MB

typedef __attribute__((ext_vector_type(8))) short bf16x8;
typedef __attribute__((ext_vector_type(4))) float f32x4;

template <bool B> struct BoolC { static constexpr bool value = B; };

__device__ __forceinline__ short f2bf(float x) {
    __hip_bfloat16 h = __float2bfloat16(x);
    return __builtin_bit_cast(short, h);
}

__device__ __forceinline__ void gload16(const void* g, void* lds) {
    __builtin_amdgcn_global_load_lds(
        (const __attribute__((address_space(1))) void*)g,
        (__attribute__((address_space(3))) void*)lds, 16, 0, 0);
}
}

// ---------------------------------------------------------------------------
// Pre-kernel: z fp32 [b][g][128] -> bf16 chunk images (8 KB / 32 g) in ws.
// Chunk c physical 16B-block p: d = p>>2, ps = p&3. Logical slot
// s = ps ^ ((d>>1)&3), g = c*32 + s*8 + j, value = bf16(z[b][g][d]).
// ---------------------------------------------------------------------------
__global__ __launch_bounds__(256)
void zcvt_kernel(const float* __restrict__ zg, short* __restrict__ img)
{
    __shared__ __align__(16) float tile[GT * 132];   // [s][d] fp32, row pad->132
    const int tid = threadIdx.x;
    const int blk = blockIdx.x;        // 512 = 4 b x 128 c
    const int c = blk & 127, b = blk >> 7;
    const float* zb = zg + ((long)(b * NG + c * GT)) * DZc;
#pragma unroll
    for (int it = 0; it < 4; ++it) {
        int f = tid + it * 256;        // 1024 float4 tiles
        int s = f >> 5, dq = f & 31;
        float4 v = *(const float4*)(zb + (long)s * DZc + dq * 4);
        *(float4*)&tile[s * 132 + dq * 4] = v;
    }
    __syncthreads();
    char* ib = (char*)img + (long)blk * CHUNK_B;
#pragma unroll
    for (int it = 0; it < 2; ++it) {
        int p = tid + it * 256;        // 16B block id 0..511
        int y = p * 16;
        int d  = p >> 2;
        int ps = p & 3;
        int s8 = (ps ^ ((d >> 1) & 3)) * 8;
        bf16x8 o;
#pragma unroll
        for (int j = 0; j < 8; ++j) o[j] = f2bf(tile[(s8 + j) * 132 + d]);
        *(bf16x8*)(ib + y) = o;
    }
}

// ---------------------------------------------------------------------------
// Main kernel: 512 blocks (b, 32t-tile) x 512 threads = 8 waves (2 wt x 4 ws).
// Wave (wt, ws): 16 t x FULL 128 d, K-quarter ws. R5-verified sync structure
// (__syncthreads per chunk). R8 = R7 minus the cvt_pk inline asm (scalar
// f2bf; compiler auto-packs per m240). EQ fast path + xg prefetch retained.
// ---------------------------------------------------------------------------
__global__ __launch_bounds__(512, 4)
void setconv_main(const float* __restrict__ xgrid, const float* __restrict__ xt,
                  const float* __restrict__ lsp, const short* __restrict__ zimg,
                  float* __restrict__ out)
{
    __shared__ __align__(16) char lds[65536];

    const int tid  = threadIdx.x;
    const int lane = tid & 63;
    const int wid  = tid >> 6;
    const int wt = wid >> 2;          // 0..1 t-stripe
    const int ws = wid & 3;           // K-quarter
    const int hi = lane >> 4;
    const int lm = lane & 15;

    // XCD swizzle: 64 consecutive lb per XCD -> 2 XCDs per b (1 MB image in L2)
    const int lb = ((blockIdx.x & 7) << 6) | (blockIdx.x >> 3);
    const int b  = lb >> 7;
    const int t0 = (lb & 127) << 5;

    float a00, a01, a10, a11;
    {
        const float LOG2E = 1.4426950408889634f;
        float cf[2][2];
#pragma unroll
        for (int d = 0; d < 2; ++d)
#pragma unroll
            for (int k = 0; k < 2; ++k) {
                float p  = lsp[d * 2 + k];
                float sp = fmaxf(p, 0.0f) + log1pf(__expf(-fabsf(p)));
                float ls = 1e-5f + sp;
                cf[d][k] = -0.5f * LOG2E / (ls * ls);
            }
        a00 = cf[0][0]; a01 = cf[0][1]; a10 = cf[1][0]; a11 = cf[1][1];
    }

    const int t = t0 + wt * 16 + lm;
    const float2 xtv = *(const float2*)&xt[((long)b * NTt + t) * 2];

    f32x4 acc[8][2];
#pragma unroll
    for (int db = 0; db < 8; ++db)
#pragma unroll
        for (int k = 0; k < 2; ++k) acc[db][k] = (f32x4){0.f, 0.f, 0.f, 0.f};

    const char* imgb = (const char*)zimg + (long)b * NCH * CHUNK_B;
    const float* xgb = xgrid + (long)b * NG * 2;

    // per-lane swizzled read base within a chunk
    const int roff = lm * 64 + ((hi ^ ((lm >> 1) & 3)) << 4);
    const char* myreg = lds + ws * 16384;

    // uniform fast path: lengthscale tiled over dx => a00==a10, a01==a11
    const bool eq = (a00 == a10) && (a01 == a11);

    auto run = [&](auto eqc) {
        constexpr bool EQv = decltype(eqc)::value;
        float4 xgN[4];     // xg prefetch for the NEXT chunk

        auto stage = [&](int i, int buf) {
#pragma unroll
            for (int r = 0; r < 4; ++r) {
                const char* src = imgb + ((long)(r * 32 + i)) * CHUNK_B + tid * 16;
                char* dst = lds + r * 16384 + buf * 8192 + tid * 16;
                gload16(src, dst);
            }
        };
        auto loadxg = [&](int c) {
            const float4* p = (const float4*)(xgb + (c * GT + hi * 8) * 2);
            xgN[0] = p[0]; xgN[1] = p[1]; xgN[2] = p[2]; xgN[3] = p[3];
        };

        stage(0, 0);
        loadxg(ws * 32);
        __syncthreads();

        for (int i = 0; i < 32; ++i) {
            const int cur = i & 1, nxt = cur ^ 1;
            if (i + 1 < 32) stage(i + 1, nxt);
            const char* rb = myreg + cur * 8192 + roff;

            // ---- A-gen from prefetched xgN (EQ path; scalar f2bf packing)
            bf16x8 A0, A1;
#pragma unroll
            for (int jp = 0; jp < 4; ++jp) {
                float4 q = xgN[jp];
                float dx0 = xtv.x - q.x, dy0 = xtv.y - q.y;
                float dx1 = xtv.x - q.z, dy1 = xtv.y - q.w;
                float w00, w01, w10, w11;
                if constexpr (EQv) {
                    float s0 = fmaf(dy0, dy0, dx0 * dx0);
                    float s1 = fmaf(dy1, dy1, dx1 * dx1);
                    w00 = __builtin_amdgcn_exp2f(s0 * a00);
                    w10 = __builtin_amdgcn_exp2f(s0 * a01);
                    w01 = __builtin_amdgcn_exp2f(s1 * a00);
                    w11 = __builtin_amdgcn_exp2f(s1 * a01);
                } else {
                    float sx0 = dx0 * dx0, sy0 = dy0 * dy0;
                    float sx1 = dx1 * dx1, sy1 = dy1 * dy1;
                    w00 = __builtin_amdgcn_exp2f(fmaf(sy0, a10, sx0 * a00));
                    w10 = __builtin_amdgcn_exp2f(fmaf(sy0, a11, sx0 * a01));
                    w01 = __builtin_amdgcn_exp2f(fmaf(sy1, a10, sx1 * a00));
                    w11 = __builtin_amdgcn_exp2f(fmaf(sy1, a11, sx1 * a01));
                }
                A0[2 * jp]     = f2bf(w00);
                A0[2 * jp + 1] = f2bf(w01);
                A1[2 * jp]     = f2bf(w10);
                A1[2 * jp + 1] = f2bf(w11);
            }

            if (i + 1 < 32) loadxg(ws * 32 + i + 1);

#pragma unroll
            for (int db = 0; db < 8; ++db) {
                bf16x8 Bf = *(const bf16x8*)(rb + db * 1024);
                acc[db][0] = __builtin_amdgcn_mfma_f32_16x16x32_bf16(A0, Bf, acc[db][0], 0, 0, 0);
                acc[db][1] = __builtin_amdgcn_mfma_f32_16x16x32_bf16(A1, Bf, acc[db][1], 0, 0, 0);
            }
            __syncthreads();
        }
    };
    if (eq) run(BoolC<true>{}); else run(BoolC<false>{});

    // -------- split-K tree reduction through LDS (verified R5) --------
    float2* area = (float2*)lds;
    const int slotA = wt * 2 + (ws >> 1);
    if (ws & 1) {
#pragma unroll
        for (int db = 0; db < 8; ++db)
#pragma unroll
            for (int r = 0; r < 4; ++r) {
                const int row = hi * 4 + r;
                area[slotA * 2048 + (db * 16 + row) * 16 + lm] =
                    (float2){acc[db][0][r], acc[db][1][r]};
            }
    }
    __syncthreads();
    if (!(ws & 1)) {
#pragma unroll
        for (int db = 0; db < 8; ++db)
#pragma unroll
            for (int r = 0; r < 4; ++r) {
                const int row = hi * 4 + r;
                float2 v = area[slotA * 2048 + (db * 16 + row) * 16 + lm];
                acc[db][0][r] += v.x;
                acc[db][1][r] += v.y;
            }
    }
    __syncthreads();
    if (ws == 2) {
#pragma unroll
        for (int db = 0; db < 8; ++db)
#pragma unroll
            for (int r = 0; r < 4; ++r) {
                const int row = hi * 4 + r;
                area[wt * 2048 + (db * 16 + row) * 16 + lm] =
                    (float2){acc[db][0][r], acc[db][1][r]};
            }
    }
    __syncthreads();
    if (ws == 0) {
#pragma unroll
        for (int db = 0; db < 8; ++db) {
            const int d = db * 16 + lm;
#pragma unroll
            for (int r = 0; r < 4; ++r) {
                const int row = hi * 4 + r;
                float2 v = area[wt * 2048 + (db * 16 + row) * 16 + lm];
                const int tt = t0 + wt * 16 + row;
                *(float2*)&out[(((long)b * NTt + tt) * DZc + d) * NKc] =
                    (float2){acc[db][0][r] + v.x, acc[db][1][r] + v.y};
            }
        }
    }
}

// ---------------------------------------------------------------------------
// Fallback (R1 kernel, known good) if ws is too small.
// ---------------------------------------------------------------------------
__global__ __launch_bounds__(256, 1)
void setconv_fused(const float* __restrict__ xgrid, const float* __restrict__ zgrid,
                   const float* __restrict__ xt, const float* __restrict__ lsp,
                   float* __restrict__ out)
{
    __shared__ __align__(16) short zt[2][DZc * 32];
    __shared__ __align__(16) float xgf[2][32 * 2];

    const int tid  = threadIdx.x;
    const int lane = tid & 63;
    const int wid  = tid >> 6;
    const int wt = wid >> 1;
    const int wd = wid & 1;
    const int hi = lane >> 4;
    const int lm = lane & 15;

    const int lb = ((blockIdx.x & 7) << 5) | (blockIdx.x >> 3);
    const int b  = lb >> 6;
    const int t0 = (lb & 63) << 6;

    float a00, a01, a10, a11;
    {
        const float LOG2E = 1.4426950408889634f;
        float cf[2][2];
#pragma unroll
        for (int d = 0; d < 2; ++d)
#pragma unroll
            for (int k = 0; k < 2; ++k) {
                float p  = lsp[d * 2 + k];
                float sp = fmaxf(p, 0.0f) + log1pf(__expf(-fabsf(p)));
                float ls = 1e-5f + sp;
                cf[d][k] = -0.5f * LOG2E / (ls * ls);
            }
        a00 = cf[0][0]; a01 = cf[0][1]; a10 = cf[1][0]; a11 = cf[1][1];
    }

    float xtx[2], xty[2];
#pragma unroll
    for (int ts = 0; ts < 2; ++ts) {
        int t = t0 + wt * 32 + ts * 16 + lm;
        const float* p = &xt[((long)b * NTt + t) * 2];
        xtx[ts] = p[0]; xty[ts] = p[1];
    }

    f32x4 acc[2][4][2];
#pragma unroll
    for (int ts = 0; ts < 2; ++ts)
#pragma unroll
        for (int db = 0; db < 4; ++db)
#pragma unroll
            for (int k = 0; k < 2; ++k)
                acc[ts][db][k] = (f32x4){0.f, 0.f, 0.f, 0.f};

    const int dcol = tid & 127;
    const int g8a  = tid >> 7;
    const long zbase = (long)b * NG * DZc;
    const int swz = (dcol >> 1) & 3;
    const int soff0 = dcol * 32 + ((g8a       ^ swz) * 8);
    const int soff1 = dcol * 32 + (((g8a + 2) ^ swz) * 8);

    float zv[16];
    float xgv = 0.f;

    auto stage_load = [&](int c) {
        const int g0 = c * 32;
        const float* zc0 = zgrid + zbase + (long)(g0 + g8a * 8) * DZc + dcol;
        const float* zc1 = zgrid + zbase + (long)(g0 + (g8a + 2) * 8) * DZc + dcol;
#pragma unroll
        for (int j = 0; j < 8; ++j) zv[j] = zc0[j * DZc];
#pragma unroll
        for (int j = 0; j < 8; ++j) zv[8 + j] = zc1[j * DZc];
        if (wid == 0) xgv = xgrid[((long)b * NG + g0) * 2 + tid];
    };

    auto stage_store = [&](int buf) {
        bf16x8 p0, p1;
#pragma unroll
        for (int j = 0; j < 8; ++j) { p0[j] = f2bf(zv[j]); p1[j] = f2bf(zv[8 + j]); }
        *(bf16x8*)&zt[buf][soff0] = p0;
        *(bf16x8*)&zt[buf][soff1] = p1;
        if (wid == 0) xgf[buf][tid] = xgv;
    };

    auto compute = [&](int buf) {
        typedef __attribute__((ext_vector_type(4))) short short4v;
        bf16x8 Bf[4];
#pragma unroll
        for (int db = 0; db < 4; ++db) {
            const int d = wd * 64 + db * 16 + lm;
            const short* zb = &zt[buf][d * 32];
            const int q = hi ^ (lm & 6);
            short4v lo = *(const short4v*)(zb + q * 4);
            short4v hh = *(const short4v*)(zb + (q ^ 4) * 4);
            Bf[db] = (bf16x8){lo.x, lo.y, lo.z, lo.w, hh.x, hh.y, hh.z, hh.w};
        }
        const float4* xp  = (const float4*)&xgf[buf][hi * 8];
        const float4* xp2 = (const float4*)&xgf[buf][32 + hi * 8];
        float4 x01 = xp[0],  x23 = xp[1];
        float4 x45 = xp2[0], x67 = xp2[1];
        float gx[8] = {x01.x, x01.z, x23.x, x23.z, x45.x, x45.z, x67.x, x67.z};
        float gy[8] = {x01.y, x01.w, x23.y, x23.w, x45.y, x45.w, x67.y, x67.w};
#pragma unroll
        for (int ts = 0; ts < 2; ++ts) {
            bf16x8 A0, A1;
#pragma unroll
            for (int j = 0; j < 8; ++j) {
                float dx = xtx[ts] - gx[j];
                float dy = xty[ts] - gy[j];
                float s0 = dx * dx, s1 = dy * dy;
                A0[j] = f2bf(__builtin_amdgcn_exp2f(s0 * a00 + s1 * a10));
                A1[j] = f2bf(__builtin_amdgcn_exp2f(s0 * a01 + s1 * a11));
            }
#pragma unroll
            for (int db = 0; db < 4; ++db) {
                acc[ts][db][0] = __builtin_amdgcn_mfma_f32_16x16x32_bf16(A0, Bf[db], acc[ts][db][0], 0, 0, 0);
                acc[ts][db][1] = __builtin_amdgcn_mfma_f32_16x16x32_bf16(A1, Bf[db], acc[ts][db][1], 0, 0, 0);
            }
        }
    };

    stage_load(0);
    stage_store(0);
    __syncthreads();

    for (int c = 0; c < NG / 32; ++c) {
        const int cur = c & 1;
        const int nxt = cur ^ 1;
        if (c + 1 < NG / 32) stage_load(c + 1);
        compute(cur);
        if (c + 1 < NG / 32) stage_store(nxt);
        __syncthreads();
    }

#pragma unroll
    for (int ts = 0; ts < 2; ++ts)
#pragma unroll
        for (int db = 0; db < 4; ++db) {
            const int d = wd * 64 + db * 16 + lm;
#pragma unroll
            for (int r = 0; r < 4; ++r) {
                const int t = t0 + wt * 32 + ts * 16 + hi * 4 + r;
                float2 v = {acc[ts][db][0][r], acc[ts][db][1][r]};
                *(float2*)&out[((long)(b * NTt + t) * DZc + d) * NKc] = v;
            }
        }
}

extern "C" void kernel_launch(void* const* d_in, const int* in_sizes, int n_in,
                              void* d_out, int out_size, void* d_ws, size_t ws_size,
                              hipStream_t stream) {
    const float* xg  = (const float*)d_in[0];   // x_grid [4,64,64,2]
    const float* zg  = (const float*)d_in[1];   // z_grid [4,64,64,128]
    const float* xtp = (const float*)d_in[2];   // xt     [4,4096,2]
    const float* ls  = (const float*)d_in[3];   // lengthscale_param [2,2]
    float* o = (float*)d_out;                   // [4,4096,256] fp32

    if (ws_size >= (size_t)IMG_BYTES) {
        short* img = (short*)d_ws;
        hipLaunchKernelGGL(zcvt_kernel, dim3(512), dim3(256), 0, stream, zg, img);
        hipLaunchKernelGGL(setconv_main, dim3(512), dim3(512), 0, stream, xg, xtp, ls, img, o);
    } else {
        hipLaunchKernelGGL(setconv_fused, dim3(256), dim3(256), 0, stream, xg, zg, xtp, ls, o);
    }
}

// Round 9
// 60.843 us; speedup vs baseline: 2.5312x; 1.0114x over previous
//
#include <hip/hip_runtime.h>
#include <hip/hip_bf16.h>

namespace {
constexpr int NG  = 4096;   // grid points per batch
constexpr int NTt = 4096;   // target points
constexpr int DZc = 128;
constexpr int NKc = 2;
constexpr int GT  = 32;     // g per chunk (one MFMA-K)
constexpr int NCH = NG / GT;                              // 128 chunks per b
constexpr long CHUNK_B   = (long)DZc * GT * 2;            // 8192 B per chunk
constexpr long IMG_BYTES = 4L * NCH * CHUNK_B;            // 4.19 MB

typedef __attribute__((ext_vector_type(8))) short bf16x8;
typedef __attribute__((ext_vector_type(4))) float f32x4;
typedef __attribute__((ext_vector_type(4))) unsigned int uintx4;

template <bool B> struct BoolC { static constexpr bool value = B; };

__device__ __forceinline__ short f2bf(float x) {
    __hip_bfloat16 h = __float2bfloat16(x);
    return __builtin_bit_cast(short, h);
}

__device__ __forceinline__ unsigned fbits(float x) {
    return __builtin_bit_cast(unsigned, x);
}

// pack hi16(we) | hi16(wo)<<16 : elem0 = we (bf16 RTZ), elem1 = wo
__device__ __forceinline__ unsigned pk_bf16(float we, float wo) {
    return __builtin_amdgcn_perm(fbits(wo), fbits(we), 0x07060302u);
}

__device__ __forceinline__ void gload16(const void* g, void* lds) {
    __builtin_amdgcn_global_load_lds(
        (const __attribute__((address_space(1))) void*)g,
        (__attribute__((address_space(3))) void*)lds, 16, 0, 0);
}
}

// ---------------------------------------------------------------------------
// Pre-kernel: z fp32 [b][g][128] -> bf16 chunk images (8 KB / 32 g) in ws.
// Chunk c physical 16B-block p: d = p>>2, ps = p&3. Logical slot
// s = ps ^ ((d>>1)&3), g = c*32 + s*8 + j, value = bf16(z[b][g][d]).
// ---------------------------------------------------------------------------
__global__ __launch_bounds__(256)
void zcvt_kernel(const float* __restrict__ zg, short* __restrict__ img)
{
    __shared__ __align__(16) float tile[GT * 132];   // [s][d] fp32, row pad->132
    const int tid = threadIdx.x;
    const int blk = blockIdx.x;        // 512 = 4 b x 128 c
    const int c = blk & 127, b = blk >> 7;
    const float* zb = zg + ((long)(b * NG + c * GT)) * DZc;
#pragma unroll
    for (int it = 0; it < 4; ++it) {
        int f = tid + it * 256;        // 1024 float4 tiles
        int s = f >> 5, dq = f & 31;
        float4 v = *(const float4*)(zb + (long)s * DZc + dq * 4);
        *(float4*)&tile[s * 132 + dq * 4] = v;
    }
    __syncthreads();
    char* ib = (char*)img + (long)blk * CHUNK_B;
#pragma unroll
    for (int it = 0; it < 2; ++it) {
        int p = tid + it * 256;        // 16B block id 0..511
        int y = p * 16;
        int d  = p >> 2;
        int ps = p & 3;
        int s8 = (ps ^ ((d >> 1) & 3)) * 8;
        bf16x8 o;
#pragma unroll
        for (int j = 0; j < 8; ++j) o[j] = f2bf(tile[(s8 + j) * 132 + d]);
        *(bf16x8*)(ib + y) = o;
    }
}

// ---------------------------------------------------------------------------
// Main kernel: 512 blocks (b, 32t-tile) x 512 threads = 8 waves (2 wt x 4 ws).
// Wave (wt, ws): 16 t x FULL 128 d, K-quarter ws. R5-verified sync structure
// (__syncthreads per chunk). R9 = R8 with v_perm_b32 bf16 packing (1 op per
// pair, RTZ centered by folding log2(1+2^-9) into the exp2 argument).
// ---------------------------------------------------------------------------
__global__ __launch_bounds__(512, 4)
void setconv_main(const float* __restrict__ xgrid, const float* __restrict__ xt,
                  const float* __restrict__ lsp, const short* __restrict__ zimg,
                  float* __restrict__ out)
{
    __shared__ __align__(16) char lds[65536];

    const int tid  = threadIdx.x;
    const int lane = tid & 63;
    const int wid  = tid >> 6;
    const int wt = wid >> 2;          // 0..1 t-stripe
    const int ws = wid & 3;           // K-quarter
    const int hi = lane >> 4;
    const int lm = lane & 15;

    // XCD swizzle: 64 consecutive lb per XCD -> 2 XCDs per b (1 MB image in L2)
    const int lb = ((blockIdx.x & 7) << 6) | (blockIdx.x >> 3);
    const int b  = lb >> 7;
    const int t0 = (lb & 127) << 5;

    float a00, a01, a10, a11;
    {
        const float LOG2E = 1.4426950408889634f;
        float cf[2][2];
#pragma unroll
        for (int d = 0; d < 2; ++d)
#pragma unroll
            for (int k = 0; k < 2; ++k) {
                float p  = lsp[d * 2 + k];
                float sp = fmaxf(p, 0.0f) + log1pf(__expf(-fabsf(p)));
                float ls = 1e-5f + sp;
                cf[d][k] = -0.5f * LOG2E / (ls * ls);
            }
        a00 = cf[0][0]; a01 = cf[0][1]; a10 = cf[1][0]; a11 = cf[1][1];
    }
    // RTZ-centering bias: truncation err [0,2^-8) -> scale by (1+2^-9) via exp arg
    const float CB = 0.002818906f;    // log2(1 + 2^-9)

    const int t = t0 + wt * 16 + lm;
    const float2 xtv = *(const float2*)&xt[((long)b * NTt + t) * 2];

    f32x4 acc[8][2];
#pragma unroll
    for (int db = 0; db < 8; ++db)
#pragma unroll
        for (int k = 0; k < 2; ++k) acc[db][k] = (f32x4){0.f, 0.f, 0.f, 0.f};

    const char* imgb = (const char*)zimg + (long)b * NCH * CHUNK_B;
    const float* xgb = xgrid + (long)b * NG * 2;

    // per-lane swizzled read base within a chunk
    const int roff = lm * 64 + ((hi ^ ((lm >> 1) & 3)) << 4);
    const char* myreg = lds + ws * 16384;

    // uniform fast path: lengthscale tiled over dx => a00==a10, a01==a11
    const bool eq = (a00 == a10) && (a01 == a11);

    auto run = [&](auto eqc) {
        constexpr bool EQv = decltype(eqc)::value;
        float4 xgN[4];     // xg prefetch for the NEXT chunk

        auto stage = [&](int i, int buf) {
#pragma unroll
            for (int r = 0; r < 4; ++r) {
                const char* src = imgb + ((long)(r * 32 + i)) * CHUNK_B + tid * 16;
                char* dst = lds + r * 16384 + buf * 8192 + tid * 16;
                gload16(src, dst);
            }
        };
        auto loadxg = [&](int c) {
            const float4* p = (const float4*)(xgb + (c * GT + hi * 8) * 2);
            xgN[0] = p[0]; xgN[1] = p[1]; xgN[2] = p[2]; xgN[3] = p[3];
        };

        stage(0, 0);
        loadxg(ws * 32);
        __syncthreads();

        for (int i = 0; i < 32; ++i) {
            const int cur = i & 1, nxt = cur ^ 1;
            if (i + 1 < 32) stage(i + 1, nxt);
            const char* rb = myreg + cur * 8192 + roff;

            // ---- A-gen from prefetched xgN (EQ path; v_perm_b32 packing)
            unsigned u0[4], u1[4];
#pragma unroll
            for (int jp = 0; jp < 4; ++jp) {
                float4 q = xgN[jp];
                float dx0 = xtv.x - q.x, dy0 = xtv.y - q.y;
                float dx1 = xtv.x - q.z, dy1 = xtv.y - q.w;
                float w00, w01, w10, w11;
                if constexpr (EQv) {
                    float s0 = fmaf(dy0, dy0, dx0 * dx0);
                    float s1 = fmaf(dy1, dy1, dx1 * dx1);
                    w00 = __builtin_amdgcn_exp2f(fmaf(s0, a00, CB));
                    w10 = __builtin_amdgcn_exp2f(fmaf(s0, a01, CB));
                    w01 = __builtin_amdgcn_exp2f(fmaf(s1, a00, CB));
                    w11 = __builtin_amdgcn_exp2f(fmaf(s1, a01, CB));
                } else {
                    float sx0 = dx0 * dx0, sy0 = dy0 * dy0;
                    float sx1 = dx1 * dx1, sy1 = dy1 * dy1;
                    w00 = __builtin_amdgcn_exp2f(fmaf(sy0, a10, fmaf(sx0, a00, CB)));
                    w10 = __builtin_amdgcn_exp2f(fmaf(sy0, a11, fmaf(sx0, a01, CB)));
                    w01 = __builtin_amdgcn_exp2f(fmaf(sy1, a10, fmaf(sx1, a00, CB)));
                    w11 = __builtin_amdgcn_exp2f(fmaf(sy1, a11, fmaf(sx1, a01, CB)));
                }
                u0[jp] = pk_bf16(w00, w01);   // k=0: elem0=g_even, elem1=g_odd
                u1[jp] = pk_bf16(w10, w11);   // k=1
            }
            bf16x8 A0 = __builtin_bit_cast(bf16x8, (uintx4){u0[0], u0[1], u0[2], u0[3]});
            bf16x8 A1 = __builtin_bit_cast(bf16x8, (uintx4){u1[0], u1[1], u1[2], u1[3]});

            if (i + 1 < 32) loadxg(ws * 32 + i + 1);

#pragma unroll
            for (int db = 0; db < 8; ++db) {
                bf16x8 Bf = *(const bf16x8*)(rb + db * 1024);
                acc[db][0] = __builtin_amdgcn_mfma_f32_16x16x32_bf16(A0, Bf, acc[db][0], 0, 0, 0);
                acc[db][1] = __builtin_amdgcn_mfma_f32_16x16x32_bf16(A1, Bf, acc[db][1], 0, 0, 0);
            }
            __syncthreads();
        }
    };
    if (eq) run(BoolC<true>{}); else run(BoolC<false>{});

    // -------- split-K tree reduction through LDS (verified R5) --------
    float2* area = (float2*)lds;
    const int slotA = wt * 2 + (ws >> 1);
    if (ws & 1) {
#pragma unroll
        for (int db = 0; db < 8; ++db)
#pragma unroll
            for (int r = 0; r < 4; ++r) {
                const int row = hi * 4 + r;
                area[slotA * 2048 + (db * 16 + row) * 16 + lm] =
                    (float2){acc[db][0][r], acc[db][1][r]};
            }
    }
    __syncthreads();
    if (!(ws & 1)) {
#pragma unroll
        for (int db = 0; db < 8; ++db)
#pragma unroll
            for (int r = 0; r < 4; ++r) {
                const int row = hi * 4 + r;
                float2 v = area[slotA * 2048 + (db * 16 + row) * 16 + lm];
                acc[db][0][r] += v.x;
                acc[db][1][r] += v.y;
            }
    }
    __syncthreads();
    if (ws == 2) {
#pragma unroll
        for (int db = 0; db < 8; ++db)
#pragma unroll
            for (int r = 0; r < 4; ++r) {
                const int row = hi * 4 + r;
                area[wt * 2048 + (db * 16 + row) * 16 + lm] =
                    (float2){acc[db][0][r], acc[db][1][r]};
            }
    }
    __syncthreads();
    if (ws == 0) {
#pragma unroll
        for (int db = 0; db < 8; ++db) {
            const int d = db * 16 + lm;
#pragma unroll
            for (int r = 0; r < 4; ++r) {
                const int row = hi * 4 + r;
                float2 v = area[wt * 2048 + (db * 16 + row) * 16 + lm];
                const int tt = t0 + wt * 16 + row;
                *(float2*)&out[(((long)b * NTt + tt) * DZc + d) * NKc] =
                    (float2){acc[db][0][r] + v.x, acc[db][1][r] + v.y};
            }
        }
    }
}

// ---------------------------------------------------------------------------
// Fallback (R1 kernel, known good) if ws is too small.
// ---------------------------------------------------------------------------
__global__ __launch_bounds__(256, 1)
void setconv_fused(const float* __restrict__ xgrid, const float* __restrict__ zgrid,
                   const float* __restrict__ xt, const float* __restrict__ lsp,
                   float* __restrict__ out)
{
    __shared__ __align__(16) short zt[2][DZc * 32];
    __shared__ __align__(16) float xgf[2][32 * 2];

    const int tid  = threadIdx.x;
    const int lane = tid & 63;
    const int wid  = tid >> 6;
    const int wt = wid >> 1;
    const int wd = wid & 1;
    const int hi = lane >> 4;
    const int lm = lane & 15;

    const int lb = ((blockIdx.x & 7) << 5) | (blockIdx.x >> 3);
    const int b  = lb >> 6;
    const int t0 = (lb & 63) << 6;

    float a00, a01, a10, a11;
    {
        const float LOG2E = 1.4426950408889634f;
        float cf[2][2];
#pragma unroll
        for (int d = 0; d < 2; ++d)
#pragma unroll
            for (int k = 0; k < 2; ++k) {
                float p  = lsp[d * 2 + k];
                float sp = fmaxf(p, 0.0f) + log1pf(__expf(-fabsf(p)));
                float ls = 1e-5f + sp;
                cf[d][k] = -0.5f * LOG2E / (ls * ls);
            }
        a00 = cf[0][0]; a01 = cf[0][1]; a10 = cf[1][0]; a11 = cf[1][1];
    }

    float xtx[2], xty[2];
#pragma unroll
    for (int ts = 0; ts < 2; ++ts) {
        int t = t0 + wt * 32 + ts * 16 + lm;
        const float* p = &xt[((long)b * NTt + t) * 2];
        xtx[ts] = p[0]; xty[ts] = p[1];
    }

    f32x4 acc[2][4][2];
#pragma unroll
    for (int ts = 0; ts < 2; ++ts)
#pragma unroll
        for (int db = 0; db < 4; ++db)
#pragma unroll
            for (int k = 0; k < 2; ++k)
                acc[ts][db][k] = (f32x4){0.f, 0.f, 0.f, 0.f};

    const int dcol = tid & 127;
    const int g8a  = tid >> 7;
    const long zbase = (long)b * NG * DZc;
    const int swz = (dcol >> 1) & 3;
    const int soff0 = dcol * 32 + ((g8a       ^ swz) * 8);
    const int soff1 = dcol * 32 + (((g8a + 2) ^ swz) * 8);

    float zv[16];
    float xgv = 0.f;

    auto stage_load = [&](int c) {
        const int g0 = c * 32;
        const float* zc0 = zgrid + zbase + (long)(g0 + g8a * 8) * DZc + dcol;
        const float* zc1 = zgrid + zbase + (long)(g0 + (g8a + 2) * 8) * DZc + dcol;
#pragma unroll
        for (int j = 0; j < 8; ++j) zv[j] = zc0[j * DZc];
#pragma unroll
        for (int j = 0; j < 8; ++j) zv[8 + j] = zc1[j * DZc];
        if (wid == 0) xgv = xgrid[((long)b * NG + g0) * 2 + tid];
    };

    auto stage_store = [&](int buf) {
        bf16x8 p0, p1;
#pragma unroll
        for (int j = 0; j < 8; ++j) { p0[j] = f2bf(zv[j]); p1[j] = f2bf(zv[8 + j]); }
        *(bf16x8*)&zt[buf][soff0] = p0;
        *(bf16x8*)&zt[buf][soff1] = p1;
        if (wid == 0) xgf[buf][tid] = xgv;
    };

    auto compute = [&](int buf) {
        typedef __attribute__((ext_vector_type(4))) short short4v;
        bf16x8 Bf[4];
#pragma unroll
        for (int db = 0; db < 4; ++db) {
            const int d = wd * 64 + db * 16 + lm;
            const short* zb = &zt[buf][d * 32];
            const int q = hi ^ (lm & 6);
            short4v lo = *(const short4v*)(zb + q * 4);
            short4v hh = *(const short4v*)(zb + (q ^ 4) * 4);
            Bf[db] = (bf16x8){lo.x, lo.y, lo.z, lo.w, hh.x, hh.y, hh.z, hh.w};
        }
        const float4* xp  = (const float4*)&xgf[buf][hi * 8];
        const float4* xp2 = (const float4*)&xgf[buf][32 + hi * 8];
        float4 x01 = xp[0],  x23 = xp[1];
        float4 x45 = xp2[0], x67 = xp2[1];
        float gx[8] = {x01.x, x01.z, x23.x, x23.z, x45.x, x45.z, x67.x, x67.z};
        float gy[8] = {x01.y, x01.w, x23.y, x23.w, x45.y, x45.w, x67.y, x67.w};
#pragma unroll
        for (int ts = 0; ts < 2; ++ts) {
            bf16x8 A0, A1;
#pragma unroll
            for (int j = 0; j < 8; ++j) {
                float dx = xtx[ts] - gx[j];
                float dy = xty[ts] - gy[j];
                float s0 = dx * dx, s1 = dy * dy;
                A0[j] = f2bf(__builtin_amdgcn_exp2f(s0 * a00 + s1 * a10));
                A1[j] = f2bf(__builtin_amdgcn_exp2f(s0 * a01 + s1 * a11));
            }
#pragma unroll
            for (int db = 0; db < 4; ++db) {
                acc[ts][db][0] = __builtin_amdgcn_mfma_f32_16x16x32_bf16(A0, Bf[db], acc[ts][db][0], 0, 0, 0);
                acc[ts][db][1] = __builtin_amdgcn_mfma_f32_16x16x32_bf16(A1, Bf[db], acc[ts][db][1], 0, 0, 0);
            }
        }
    };

    stage_load(0);
    stage_store(0);
    __syncthreads();

    for (int c = 0; c < NG / 32; ++c) {
        const int cur = c & 1;
        const int nxt = cur ^ 1;
        if (c + 1 < NG / 32) stage_load(c + 1);
        compute(cur);
        if (c + 1 < NG / 32) stage_store(nxt);
        __syncthreads();
    }

#pragma unroll
    for (int ts = 0; ts < 2; ++ts)
#pragma unroll
        for (int db = 0; db < 4; ++db) {
            const int d = wd * 64 + db * 16 + lm;
#pragma unroll
            for (int r = 0; r < 4; ++r) {
                const int t = t0 + wt * 32 + ts * 16 + hi * 4 + r;
                float2 v = {acc[ts][db][0][r], acc[ts][db][1][r]};
                *(float2*)&out[((long)(b * NTt + t) * DZc + d) * NKc] = v;
            }
        }
}

extern "C" void kernel_launch(void* const* d_in, const int* in_sizes, int n_in,
                              void* d_out, int out_size, void* d_ws, size_t ws_size,
                              hipStream_t stream) {
    const float* xg  = (const float*)d_in[0];   // x_grid [4,64,64,2]
    const float* zg  = (const float*)d_in[1];   // z_grid [4,64,64,128]
    const float* xtp = (const float*)d_in[2];   // xt     [4,4096,2]
    const float* ls  = (const float*)d_in[3];   // lengthscale_param [2,2]
    float* o = (float*)d_out;                   // [4,4096,256] fp32

    if (ws_size >= (size_t)IMG_BYTES) {
        short* img = (short*)d_ws;
        hipLaunchKernelGGL(zcvt_kernel, dim3(512), dim3(256), 0, stream, zg, img);
        hipLaunchKernelGGL(setconv_main, dim3(512), dim3(512), 0, stream, xg, xtp, ls, img, o);
    } else {
        hipLaunchKernelGGL(setconv_fused, dim3(256), dim3(256), 0, stream, xg, zg, xtp, ls, o);
    }
}